// Round 2
// baseline (94.704 us; speedup 1.0000x reference)
//
#include <hip/hip_runtime.h>
#include <math.h>

#define H 2048
#define DIN 1024
#define DOUT 1024
#define NL 4

__device__ __forceinline__ float wave_reduce_sum(float v) {
    #pragma unroll
    for (int off = 32; off; off >>= 1) v += __shfl_down(v, off);
    return v;
}

// Generic GEMV: y[r] = dot(W[r,:], x) + b[r]. One 64-lane wave per row.
template <int K>
__global__ void gemv_kernel(const float* __restrict__ W, const float* __restrict__ x,
                            const float* __restrict__ b, float* __restrict__ y, int N) {
    int wave = (blockIdx.x * blockDim.x + threadIdx.x) >> 6;
    int lane = threadIdx.x & 63;
    if (wave >= N) return;
    const float* row = W + (size_t)wave * K;
    float acc = 0.f;
    #pragma unroll
    for (int i = 0; i < K / 256; ++i) {
        int idx = i * 256 + lane * 4;
        float4 w  = *reinterpret_cast<const float4*>(row + idx);
        float4 xv = *reinterpret_cast<const float4*>(x + idx);
        acc = fmaf(w.x, xv.x, acc); acc = fmaf(w.y, xv.y, acc);
        acc = fmaf(w.z, xv.z, acc); acc = fmaf(w.w, xv.w, acc);
    }
    acc = wave_reduce_sum(acc);
    if (lane == 0) y[wave] = acc + b[wave];
}

// Fully fused per-layer GRU step: one wave per output element.
// 6 dots per wave: {r,z,n} x {W_ih over carry, W_hh over h0[l]} + gate math.
// Writes h_new to both the ping-pong carry and the d_out hidden slot.
// ws usage in this design: only 2*H floats (16 KB) — no gh scratch.
__global__ void gru_layer_kernel(const float* __restrict__ Wi,    // [3H, H] this layer
                                 const float* __restrict__ Wh,    // [3H, H] this layer
                                 const float* __restrict__ bi,    // [3H]
                                 const float* __restrict__ bh,    // [3H]
                                 const float* __restrict__ hprev, // [H] = h0[l]
                                 const float* __restrict__ cin,   // [H]
                                 float* __restrict__ cout,        // [H]
                                 float* __restrict__ hid_out) {   // [H] slice of d_out
    int wave = (blockIdx.x * blockDim.x + threadIdx.x) >> 6;
    int lane = threadIdx.x & 63;
    if (wave >= H) return;
    const float* ir_row = Wi + (size_t)wave * H;
    const float* iz_row = Wi + (size_t)(wave + H) * H;
    const float* in_row = Wi + (size_t)(wave + 2 * H) * H;
    const float* hr_row = Wh + (size_t)wave * H;
    const float* hz_row = Wh + (size_t)(wave + H) * H;
    const float* hn_row = Wh + (size_t)(wave + 2 * H) * H;
    float air = 0.f, aiz = 0.f, ain = 0.f;
    float ahr = 0.f, ahz = 0.f, ahn = 0.f;
    #pragma unroll
    for (int i = 0; i < H / 256; ++i) {
        int idx = i * 256 + lane * 4;
        float4 xv = *reinterpret_cast<const float4*>(cin + idx);
        float4 hv = *reinterpret_cast<const float4*>(hprev + idx);
        float4 w0 = *reinterpret_cast<const float4*>(ir_row + idx);
        float4 w1 = *reinterpret_cast<const float4*>(iz_row + idx);
        float4 w2 = *reinterpret_cast<const float4*>(in_row + idx);
        float4 w3 = *reinterpret_cast<const float4*>(hr_row + idx);
        float4 w4 = *reinterpret_cast<const float4*>(hz_row + idx);
        float4 w5 = *reinterpret_cast<const float4*>(hn_row + idx);
        air = fmaf(w0.x, xv.x, air); air = fmaf(w0.y, xv.y, air);
        air = fmaf(w0.z, xv.z, air); air = fmaf(w0.w, xv.w, air);
        aiz = fmaf(w1.x, xv.x, aiz); aiz = fmaf(w1.y, xv.y, aiz);
        aiz = fmaf(w1.z, xv.z, aiz); aiz = fmaf(w1.w, xv.w, aiz);
        ain = fmaf(w2.x, xv.x, ain); ain = fmaf(w2.y, xv.y, ain);
        ain = fmaf(w2.z, xv.z, ain); ain = fmaf(w2.w, xv.w, ain);
        ahr = fmaf(w3.x, hv.x, ahr); ahr = fmaf(w3.y, hv.y, ahr);
        ahr = fmaf(w3.z, hv.z, ahr); ahr = fmaf(w3.w, hv.w, ahr);
        ahz = fmaf(w4.x, hv.x, ahz); ahz = fmaf(w4.y, hv.y, ahz);
        ahz = fmaf(w4.z, hv.z, ahz); ahz = fmaf(w4.w, hv.w, ahz);
        ahn = fmaf(w5.x, hv.x, ahn); ahn = fmaf(w5.y, hv.y, ahn);
        ahn = fmaf(w5.z, hv.z, ahn); ahn = fmaf(w5.w, hv.w, ahn);
    }
    air = wave_reduce_sum(air);
    aiz = wave_reduce_sum(aiz);
    ain = wave_reduce_sum(ain);
    ahr = wave_reduce_sum(ahr);
    ahz = wave_reduce_sum(ahz);
    ahn = wave_reduce_sum(ahn);
    if (lane == 0) {
        float ir  = air + bi[wave];
        float iz  = aiz + bi[H + wave];
        float inn = ain + bi[2 * H + wave];
        float hr  = ahr + bh[wave];
        float hz  = ahz + bh[H + wave];
        float hn  = ahn + bh[2 * H + wave];
        float r = 1.f / (1.f + expf(-(ir + hr)));
        float z = 1.f / (1.f + expf(-(iz + hz)));
        float n = tanhf(inn + r * hn);
        float h = hprev[wave];
        float hnew = (1.f - z) * n + z * h;
        cout[wave] = hnew;
        hid_out[wave] = hnew;
    }
}

extern "C" void kernel_launch(void* const* d_in, const int* in_sizes, int n_in,
                              void* d_out, int out_size, void* d_ws, size_t ws_size,
                              hipStream_t stream) {
    const float* x    = (const float*)d_in[0];
    const float* h0   = (const float*)d_in[1];
    const float* encW = (const float*)d_in[2];
    const float* encb = (const float*)d_in[3];
    const float* Wih  = (const float*)d_in[4];
    const float* Whh  = (const float*)d_in[5];
    const float* bih  = (const float*)d_in[6];
    const float* bhh  = (const float*)d_in[7];
    const float* decW = (const float*)d_in[8];
    const float* decb = (const float*)d_in[9];
    float* out = (float*)d_out;

    // Only 16 KB of d_ws used (R1 post-mortem: 112 KB gh scratch overflowed
    // ws_size and corrupted an input buffer -> replay divergence).
    float* vec0 = (float*)d_ws;      // [H]
    float* vec1 = vec0 + H;          // [H]

    // 1) encoder: [1,1024] -> [1,2048]
    gemv_kernel<DIN><<<H / 4, 256, 0, stream>>>(encW, x, encb, vec0, H);
    // 2) sequential fused GRU layers, ping-pong carry
    const float* cin = vec0;
    float* cout = vec1;
    for (int l = 0; l < NL; ++l) {
        gru_layer_kernel<<<H / 4, 256, 0, stream>>>(
            Wih + (size_t)l * 3 * H * H, Whh + (size_t)l * 3 * H * H,
            bih + l * 3 * H, bhh + l * 3 * H,
            h0 + l * H, cin, cout, out + DOUT + l * H);
        float* t = cout; cout = (float*)cin; cin = t;
    }
    // 3) decoder: [1,2048] -> [1,1024]
    gemv_kernel<H><<<DOUT / 4, 256, 0, stream>>>(decW, cin, decb, out, DOUT);
}